// Round 1
// baseline (649.699 us; speedup 1.0000x reference)
//
#include <hip/hip_runtime.h>
#include <hip/hip_bf16.h>
#include <math.h>

#define F_IN 128
#define C1 16
#define C2 8

#define LBITS 8                 // 256 nodes per scan bucket
#define LOCAL (1 << LBITS)
#define NB_MAX 512              // supports N up to 131072
#define HISTBLK 512             // blocks of the fused kernel doing histogram

static __device__ __forceinline__ unsigned short f2bf(float f) {
  __hip_bfloat16 h = __float2bfloat16(f);
  return *(unsigned short*)&h;
}

// ---------------- fused: per-node histogram + layer-1 dense transforms ----------------
// Blocks [0, HISTBLK) histogram dst into global ncount[N] (400KB, L2-resident,
// avg 32 increments per address -> negligible contention). Blocks [HISTBLK, ...)
// run the matrix-split gemm with a 16-deep float4 register pipeline (the old
// version had VGPR=28 and ~no loads in flight -> latency-bound at 2 TB/s).
__global__ __launch_bounds__(256) void hist_gemm(
    const int* __restrict__ dst, int* __restrict__ ncount, int E,
    const float* __restrict__ x, const float* __restrict__ Wl, const float* __restrict__ Wr,
    const float* __restrict__ Wlin, const float* __restrict__ blin,
    __hip_bfloat16* __restrict__ XLh, float* __restrict__ XR, float* __restrict__ SK, int N) {
  if (blockIdx.x < HISTBLK) {
    int stride = HISTBLK * 256;
    int tid = blockIdx.x * 256 + threadIdx.x;
    int n4 = E >> 2;
    const int4* d4 = (const int4*)dst;
    for (int i = tid; i < n4; i += stride) {
      int4 d = d4[i];
      atomicAdd(&ncount[d.x], 1);
      atomicAdd(&ncount[d.y], 1);
      atomicAdd(&ncount[d.z], 1);
      atomicAdd(&ncount[d.w], 1);
    }
    if (tid == 0) {
      for (int e = n4 * 4; e < E; e++) atomicAdd(&ncount[dst[e]], 1);
    }
  } else {
    int bx = blockIdx.x - HISTBLK;
    int mat = bx % 3;
    int node = (bx / 3) * 256 + threadIdx.x;
    if (node >= N) return;
    const float* __restrict__ W = (mat == 0) ? Wl : (mat == 1) ? Wr : Wlin;
    const float4* xr4 = (const float4*)(x + (size_t)node * F_IN);
    // Issue all 32 dwordx4 loads up front (two 8-deep buffers) for deep MLP.
    float4 xa[8], xb[8];
#pragma unroll
    for (int q = 0; q < 8; q++) xa[q] = xr4[q];
#pragma unroll
    for (int q = 0; q < 8; q++) xb[q] = xr4[8 + q];
    float acc[16];
#pragma unroll
    for (int c = 0; c < 16; c++) acc[c] = 0.f;
#pragma unroll
    for (int q = 0; q < 8; q++) {
      float xs[4] = {xa[q].x, xa[q].y, xa[q].z, xa[q].w};
#pragma unroll
      for (int j = 0; j < 4; j++) {
        int k = q * 4 + j;
#pragma unroll
        for (int c = 0; c < 16; c++) acc[c] = fmaf(xs[j], W[k * 16 + c], acc[c]);
      }
    }
#pragma unroll
    for (int q = 0; q < 8; q++) {
      float xs[4] = {xb[q].x, xb[q].y, xb[q].z, xb[q].w};
#pragma unroll
      for (int j = 0; j < 4; j++) {
        int k = 32 + q * 4 + j;
#pragma unroll
        for (int c = 0; c < 16; c++) acc[c] = fmaf(xs[j], W[k * 16 + c], acc[c]);
      }
    }
    if (mat == 0) {
      unsigned int pk[8];
#pragma unroll
      for (int i = 0; i < 8; i++)
        pk[i] = (unsigned)f2bf(acc[2 * i]) | ((unsigned)f2bf(acc[2 * i + 1]) << 16);
      uint4* xlp = (uint4*)(XLh + (size_t)node * 16);
      xlp[0] = make_uint4(pk[0], pk[1], pk[2], pk[3]);
      xlp[1] = make_uint4(pk[4], pk[5], pk[6], pk[7]);
    } else if (mat == 1) {
      float4* xrp = (float4*)(XR + (size_t)node * 16);
#pragma unroll
      for (int q = 0; q < 4; q++)
        xrp[q] = make_float4(acc[4 * q], acc[4 * q + 1], acc[4 * q + 2], acc[4 * q + 3]);
    } else {
      float4* skp = (float4*)(SK + (size_t)node * 16);
#pragma unroll
      for (int q = 0; q < 4; q++)
        skp[q] = make_float4(acc[4 * q] + blin[4 * q], acc[4 * q + 1] + blin[4 * q + 1],
                             acc[4 * q + 2] + blin[4 * q + 2], acc[4 * q + 3] + blin[4 * q + 3]);
    }
  }
}

// Per-bucket (256-node) exclusive scan of ncount, in place; bucket total -> bsum.
__global__ __launch_bounds__(256) void scan_nodes(int* __restrict__ ncount,
                                                  int* __restrict__ bsum, int N) {
  __shared__ int sd[LOCAL];
  int b = blockIdx.x, t = threadIdx.x;
  int node = (b << LBITS) + t;
  int v = (node < N) ? ncount[node] : 0;
  sd[t] = v;
  __syncthreads();
  int acc = v;
  for (int off = 1; off < LOCAL; off <<= 1) {
    int u = (t >= off) ? sd[t - off] : 0;
    __syncthreads();
    acc += u;
    sd[t] = acc;
    __syncthreads();
  }
  if (node < N) ncount[node] = acc - v;  // exclusive-within-bucket
  if (t == LOCAL - 1) bsum[b] = acc;
}

// Scan the NB bucket totals -> bbase (exclusive), bbase[NB] = E.
__global__ void bucket_scan(const int* __restrict__ bsum, int* __restrict__ bbase, int NB) {
  __shared__ int sd[NB_MAX];
  int t = threadIdx.x;
  int v = (t < NB) ? bsum[t] : 0;
  sd[t] = v;
  __syncthreads();
  int acc = v;
  for (int off = 1; off < NB_MAX; off <<= 1) {
    int u = (t >= off) ? sd[t - off] : 0;
    __syncthreads();
    acc += u;
    sd[t] = acc;
    __syncthreads();
  }
  if (t < NB) {
    bbase[t] = acc - v;
    if (t == NB - 1) bbase[NB] = acc;
  }
}

// row_ptr[node] = bbase[bucket] + within-bucket exclusive; cursor = copy for scatter.
__global__ __launch_bounds__(256) void finalize_rp(const int* __restrict__ ncount,
                                                   const int* __restrict__ bbase,
                                                   int* __restrict__ row_ptr,
                                                   int* __restrict__ cursor, int N, int E) {
  int b = blockIdx.x, t = threadIdx.x;
  int node = (b << LBITS) + t;
  if (node < N) {
    int rp = bbase[b] + ncount[node];
    row_ptr[node] = rp;
    cursor[node] = rp;
  }
  if (b == 0 && t == 0) row_ptr[N] = E;
}

// Direct CSR scatter: p = cursor[dst]++; ssrc[p] = (src<<5)|(dst&31).
// Scattered 4B writes land in L2 and evict as fully-dirty lines (HBM write
// traffic stays 12.8MB); cursor atomics are L2-resident, ~32 hits/address.
__global__ __launch_bounds__(256) void scatter_edges(const int* __restrict__ src,
                                                     const int* __restrict__ dst,
                                                     int* __restrict__ cursor,
                                                     int* __restrict__ ssrc, int E) {
  int tid = blockIdx.x * 256 + threadIdx.x;
  int n4 = E >> 2;
  const int4* s4 = (const int4*)src;
  const int4* d4 = (const int4*)dst;
  if (tid < n4) {
    int4 s = s4[tid];
    int4 d = d4[tid];
    int p0 = atomicAdd(&cursor[d.x], 1);
    int p1 = atomicAdd(&cursor[d.y], 1);
    int p2 = atomicAdd(&cursor[d.z], 1);
    int p3 = atomicAdd(&cursor[d.w], 1);
    ssrc[p0] = (s.x << 5) | (d.x & 31);
    ssrc[p1] = (s.y << 5) | (d.y & 31);
    ssrc[p2] = (s.z << 5) | (d.z & 31);
    ssrc[p3] = (s.w << 5) | (d.w & 31);
  }
  if (blockIdx.x == 0 && threadIdx.x < (E & 3)) {
    int e = n4 * 4 + threadIdx.x;
    int s = src[e], d = dst[e];
    int p = atomicAdd(&cursor[d], 1);
    ssrc[p] = (s << 5) | (d & 31);
  }
}

// ---------------- GAT layer ----------------
// hsh aliases vpool (dead after phase 2; barrier-protected) to save LDS -> 7 blocks/CU.
template <int C, int POOL, bool HEAD, bool FUSEG2>
__global__ __launch_bounds__(256) void gat_layer(
    const __hip_bfloat16* __restrict__ XLh, const float* __restrict__ XR,
    const float* __restrict__ SK, const float* __restrict__ att, const float* __restrict__ bias,
    const float* __restrict__ tp, const int* __restrict__ row_ptr, const int* __restrict__ ssrc,
    float* __restrict__ H, int N,
    const float* __restrict__ P0, const float* __restrict__ P1, const float* __restrict__ P2,
    const float* __restrict__ P3, const float* __restrict__ P4, const float* __restrict__ P5,
    const float* __restrict__ P6, const float* __restrict__ P7,
    __hip_bfloat16* __restrict__ XL2h, float* __restrict__ XR2, float* __restrict__ SK2,
    float* __restrict__ out) {
  constexpr int NPB = 256 / C;
  __shared__ __align__(16) unsigned short vpool[POOL * C];
  __shared__ float ppool[POOL];
  __shared__ __align__(16) float xrl[NPB * C];
  __shared__ int nb[NPB + 1];
  __shared__ float wfuse[FUSEG2 ? 392 : 1];
  float* hsh = (float*)vpool;  // aliased: used only after phase 2 (barrier-protected)
  int t = threadIdx.x;
  int node0 = blockIdx.x * NPB;

  if (t <= NPB) {
    int nd = node0 + t;
    nb[t] = row_ptr[(nd < N) ? nd : N];
  }
  {
    size_t xi = (size_t)node0 * C + t;
    xrl[t] = (xi < (size_t)N * C) ? XR[xi] : 0.f;
  }
  if constexpr (FUSEG2) {
    for (int i = t; i < 392; i += 256)
      wfuse[i] = (i < 128) ? P0[i] : (i < 256) ? P1[i - 128] : (i < 384) ? P2[i - 256] : P3[i - 384];
  }
  float attr[C];
#pragma unroll
  for (int cc = 0; cc < C; cc++) attr[cc] = att[cc];
  float tval = tp[0];
  __syncthreads();

  int bbeg = nb[0];
  int nE = nb[NPB] - bbeg;
  int nCap = (nE < POOL) ? nE : POOL;
  const unsigned short* XLu = (const unsigned short*)XLh;

  // ---- Phase S: edge-per-lane gather + score ----
  for (int slot = t; slot < nCap; slot += 256) {
    int sp = ssrc[bbeg + slot];
    int s = sp >> 5;
    int g = sp & (NPB - 1);
    float v[C];
    if constexpr (C == 16) {
      const uint4* gp = (const uint4*)(XLu + (size_t)s * 16);
      uint4 a = gp[0], b = gp[1];
      *(uint4*)&vpool[slot * 16] = a;
      *(uint4*)&vpool[slot * 16 + 8] = b;
      unsigned arr[8] = {a.x, a.y, a.z, a.w, b.x, b.y, b.z, b.w};
#pragma unroll
      for (int i = 0; i < 8; i++) {
        v[2 * i] = __uint_as_float(arr[i] << 16);
        v[2 * i + 1] = __uint_as_float(arr[i] & 0xffff0000u);
      }
    } else {
      const uint4* gp = (const uint4*)(XLu + (size_t)s * 8);
      uint4 a = gp[0];
      *(uint4*)&vpool[slot * 8] = a;
      unsigned arr[4] = {a.x, a.y, a.z, a.w};
#pragma unroll
      for (int i = 0; i < 4; i++) {
        v[2 * i] = __uint_as_float(arr[i] << 16);
        v[2 * i + 1] = __uint_as_float(arr[i] & 0xffff0000u);
      }
    }
    float xr[C];
    const float4* xp = (const float4*)&xrl[g * C];
#pragma unroll
    for (int q = 0; q < C / 4; q++) {
      float4 f = xp[q];
      xr[4 * q] = f.x;
      xr[4 * q + 1] = f.y;
      xr[4 * q + 2] = f.z;
      xr[4 * q + 3] = f.w;
    }
    float p0 = 0.f, p1 = 0.f, p2 = 0.f, p3 = 0.f;
#pragma unroll
    for (int cc = 0; cc < C; cc += 4) {
      float u0 = v[cc] + xr[cc];
      float u1 = v[cc + 1] + xr[cc + 1];
      float u2 = v[cc + 2] + xr[cc + 2];
      float u3 = v[cc + 3] + xr[cc + 3];
      p0 = fmaf(fmaxf(u0, 0.2f * u0), attr[cc], p0);
      p1 = fmaf(fmaxf(u1, 0.2f * u1), attr[cc + 1], p1);
      p2 = fmaf(fmaxf(u2, 0.2f * u2), attr[cc + 2], p2);
      p3 = fmaf(fmaxf(u3, 0.2f * u3), attr[cc + 3], p3);
    }
    ppool[slot] = __expf((p0 + p1) + (p2 + p3));
  }
  __syncthreads();

  int g = t / C;
  int c = t % C;
  int base = nb[g] - bbeg;
  int deg = nb[g + 1] - nb[g];
  int capd = POOL - base;
  capd = capd < 0 ? 0 : (capd > deg ? deg : capd);

  // ---- Phase D: S0 per node ----
  float invS0;
  {
    float s0 = 0.f;
    for (int j = c; j < capd; j += C) s0 += ppool[base + j];
    for (int j = capd + c; j < deg; j += C) {  // overflow fallback (rare)
      int s = ssrc[bbeg + base + j] >> 5;
      float sc = 0.f;
#pragma unroll
      for (int cc = 0; cc < C; cc++) {
        float v = __bfloat162float(XLh[(size_t)s * C + cc]);
        float u = v + xrl[g * C + cc];
        sc = fmaf(fmaxf(u, 0.2f * u), attr[cc], sc);
      }
      s0 += __expf(sc);
    }
#pragma unroll
    for (int m = 1; m < C; m <<= 1) s0 += __shfl_xor(s0, m, C);
    invS0 = (deg > 0) ? 1.0f / s0 : 0.f;
  }
  float a = invS0 * tval;

  // ---- Phase 2: q = v*p*a; w = exp(q); S1 += w; S2 += w*q ----
  float S1 = 0.f, S2 = 0.f, S1b = 0.f, S2b = 0.f;
  int jj = 0;
  for (; jj + 2 <= capd; jj += 2) {
    int sl0 = base + jj;
    float v0 = __uint_as_float(((unsigned)vpool[sl0 * C + c]) << 16);
    float q0 = v0 * ppool[sl0] * a;
    float v1 = __uint_as_float(((unsigned)vpool[(sl0 + 1) * C + c]) << 16);
    float q1 = v1 * ppool[sl0 + 1] * a;
    float w0 = __expf(q0);
    float w1 = __expf(q1);
    S1 += w0;
    S2 = fmaf(w0, q0, S2);
    S1b += w1;
    S2b = fmaf(w1, q1, S2b);
  }
  for (; jj < capd; jj++) {
    int sl = base + jj;
    float v = __uint_as_float(((unsigned)vpool[sl * C + c]) << 16);
    float q = v * ppool[sl] * a;
    float w = __expf(q);
    S1 += w;
    S2 = fmaf(w, q, S2);
  }
  for (; jj < deg; jj++) {  // overflow fallback (rare)
    int s = ssrc[bbeg + base + jj] >> 5;
    float sc = 0.f, vc = 0.f;
#pragma unroll
    for (int cc = 0; cc < C; cc++) {
      float v = __bfloat162float(XLh[(size_t)s * C + cc]);
      if (cc == c) vc = v;
      float u = v + xrl[g * C + cc];
      sc = fmaf(fmaxf(u, 0.2f * u), attr[cc], sc);
    }
    float p = __expf(sc);
    float q = vc * p * a;
    float w = __expf(q);
    S1 += w;
    S2 = fmaf(w, q, S2);
  }
  S1 += S1b;
  S2 += S2b;

  int node = node0 + g;
  bool valid = node < N;
  float hval = 0.f;
  if (valid) {
    float td = (tval != 0.f) ? tval : 1.f;
    float gat = (deg > 0) ? (S2 / (S1 * td)) : 0.f;
    hval = fmaxf(gat + bias[c] + SK[(size_t)node * C + c], 0.f);
  }
  if constexpr (FUSEG2) {
    __syncthreads();  // vpool dead; hsh aliases it
    hsh[g * C + c] = hval;
    __syncthreads();
    if (t < NPB * 8) {
      int g2 = t >> 3, c2 = t & 7;
      int nd = node0 + g2;
      if (nd < N) {
        float a0 = 0.f, a1 = 0.f, a2 = 0.f;
#pragma unroll
        for (int k = 0; k < 16; k++) {
          float hv = hsh[g2 * 16 + k];
          a0 = fmaf(hv, wfuse[k * 8 + c2], a0);
          a1 = fmaf(hv, wfuse[128 + k * 8 + c2], a1);
          a2 = fmaf(hv, wfuse[256 + k * 8 + c2], a2);
        }
        ((unsigned short*)XL2h)[(size_t)nd * 8 + c2] = f2bf(a0);
        XR2[(size_t)nd * 8 + c2] = a1;
        SK2[(size_t)nd * 8 + c2] = a2 + wfuse[384 + c2];
      }
    }
  } else if constexpr (HEAD) {
    __syncthreads();  // vpool dead; hsh aliases it
    hsh[g * C + c] = hval;
    __syncthreads();
    if (t < NPB) {
      int nd = node0 + t;
      if (nd < N) {
        float h[8];
#pragma unroll
        for (int k = 0; k < 8; k++) h[k] = hsh[t * 8 + k];
        float s4 = 0.f;
#pragma unroll
        for (int cc = 0; cc < 8; cc++) {
          float z = P1[cc];  // b3
#pragma unroll
          for (int k = 0; k < 8; k++) z = fmaf(h[k], P0[k * 8 + cc], z);  // W3
          z = fmaxf(z, 0.f);
          s4 = fmaf(z, P2[cc], s4);  // W4
        }
        s4 = fmaxf(s4 + P3[0], 0.f);                    // b4
        float s5 = fmaxf(fmaf(s4, P4[0], P5[0]), 0.f);  // W5,b5
        float zo = fmaf(s5, P6[0], P7[0]);              // Wout,bout
        float ls;
        if (zo >= 0.f)
          ls = -log1pf(expf(-zo));
        else
          ls = zo - log1pf(expf(zo));
        out[nd] = ls;
      }
    }
  } else {
    if (valid) H[(size_t)node * C + c] = hval;
  }
}

extern "C" void kernel_launch(void* const* d_in, const int* in_sizes, int n_in,
                              void* d_out, int out_size, void* d_ws, size_t ws_size,
                              hipStream_t stream) {
  const float* x = (const float*)d_in[0];
  const int* ei = (const int*)d_in[1];
  const float* Wl1 = (const float*)d_in[3];
  const float* Wr1 = (const float*)d_in[4];
  const float* att1 = (const float*)d_in[5];
  const float* b1 = (const float*)d_in[6];
  const float* Wlin1 = (const float*)d_in[7];
  const float* blin1 = (const float*)d_in[8];
  const float* Wl2 = (const float*)d_in[9];
  const float* Wr2 = (const float*)d_in[10];
  const float* att2 = (const float*)d_in[11];
  const float* b2 = (const float*)d_in[12];
  const float* Wlin2 = (const float*)d_in[13];
  const float* blin2 = (const float*)d_in[14];
  const float* t = (const float*)d_in[15];
  const float* W3 = (const float*)d_in[16];
  const float* b3 = (const float*)d_in[17];
  const float* W4 = (const float*)d_in[18];
  const float* b4 = (const float*)d_in[19];
  const float* W5 = (const float*)d_in[20];
  const float* b5 = (const float*)d_in[21];
  const float* Wout = (const float*)d_in[22];
  const float* bout = (const float*)d_in[23];
  float* out = (float*)d_out;

  int N = in_sizes[0] / F_IN;
  int E = in_sizes[1] / 2;
  const int* src = ei;
  const int* dst = ei + E;
  int NB = (N + LOCAL - 1) >> LBITS;  // 391 for N=100000

  char* ws = (char*)d_ws;
  size_t off = 0;
  auto alloc = [&](size_t bytes) -> void* {
    void* p = ws + off;
    off = (off + bytes + 255) & ~(size_t)255;
    return p;
  };
  int* ncount = (int*)alloc((size_t)N * 4);        // hist -> in-place within-bucket excl scan
  int* bsum = (int*)alloc((size_t)NB * 4);
  int* bbase = (int*)alloc((size_t)(NB + 1) * 4);
  int* row_ptr = (int*)alloc((size_t)(N + 1) * 4);
  int* cursor = (int*)alloc((size_t)N * 4);
  int* ssrc = (int*)alloc((size_t)E * 4);
  __hip_bfloat16* XL1 = (__hip_bfloat16*)alloc((size_t)N * C1 * 2);
  float* XR1 = (float*)alloc((size_t)N * C1 * 4);
  float* SK1 = (float*)alloc((size_t)N * C1 * 4);
  __hip_bfloat16* XL2 = (__hip_bfloat16*)alloc((size_t)N * C2 * 2);
  float* XR2 = (float*)alloc((size_t)N * C2 * 4);
  float* SK2 = (float*)alloc((size_t)N * C2 * 4);

  int nodeBlk = (N + 255) / 256;  // 391
  int nblkS = ((E >> 2) + 255) / 256;
  if (nblkS < 1) nblkS = 1;

  hipMemsetAsync(ncount, 0, (size_t)N * 4, stream);
  hipLaunchKernelGGL(hist_gemm, dim3(HISTBLK + nodeBlk * 3), dim3(256), 0, stream, dst, ncount, E,
                     x, Wl1, Wr1, Wlin1, blin1, XL1, XR1, SK1, N);
  hipLaunchKernelGGL(scan_nodes, dim3(NB), dim3(LOCAL), 0, stream, ncount, bsum, N);
  hipLaunchKernelGGL(bucket_scan, dim3(1), dim3(NB_MAX), 0, stream, bsum, bbase, NB);
  hipLaunchKernelGGL(finalize_rp, dim3(NB), dim3(LOCAL), 0, stream, ncount, bbase, row_ptr, cursor,
                     N, E);
  hipLaunchKernelGGL(scatter_edges, dim3(nblkS), dim3(256), 0, stream, src, dst, cursor, ssrc, E);
  hipLaunchKernelGGL((gat_layer<16, 576, false, true>), dim3((N + 15) / 16), dim3(256), 0, stream,
                     XL1, XR1, SK1, att1, b1, t, row_ptr, ssrc, nullptr, N, Wl2, Wr2, Wlin2, blin2,
                     nullptr, nullptr, nullptr, nullptr, XL2, XR2, SK2, nullptr);
  hipLaunchKernelGGL((gat_layer<8, 1216, true, false>), dim3((N + 31) / 32), dim3(256), 0, stream,
                     XL2, XR2, SK2, att2, b2, t, row_ptr, ssrc, nullptr, N, W3, b3, W4, b4, W5, b5,
                     Wout, bout, nullptr, nullptr, nullptr, out);
}

// Round 2
// 303.568 us; speedup vs baseline: 2.1402x; 2.1402x over previous
//
#include <hip/hip_runtime.h>
#include <hip/hip_bf16.h>
#include <math.h>

#define F_IN 128
#define C1 16
#define C2 8

#define LBITS 8                 // 256 nodes per bucket
#define LOCAL (1 << LBITS)
#define NB_MAX 512              // supports N up to 131072
#define ITEMS 16                // edges per thread in phase A
#define EPB (256 * ITEMS)       // 4096 edges per phase-A block
#define HISTBLK 512             // blocks of the fused kernel doing histogram

static __device__ __forceinline__ unsigned short f2bf(float f) {
  __hip_bfloat16 h = __float2bfloat16(f);
  return *(unsigned short*)&h;
}

// ---------------- fused: bucket histogram + layer-1 dense transforms ----------------
// Blocks [0, HISTBLK) histogram dst>>LBITS; blocks [HISTBLK, ...) run the
// matrix-split gemm (independent work — co-scheduling overlaps their stalls).
// GEMM half issues all 32 dwordx4 x-row loads up front (two 8-deep register
// buffers) so the wave has ~16 loads in flight instead of ~2 (old VGPR=28
// build was latency-bound at 2 TB/s, VALUBusy 15%).
__global__ __launch_bounds__(256) void hist_gemm(
    const int* __restrict__ dst, int* __restrict__ bcount, int E, int NB,
    const float* __restrict__ x, const float* __restrict__ Wl, const float* __restrict__ Wr,
    const float* __restrict__ Wlin, const float* __restrict__ blin,
    __hip_bfloat16* __restrict__ XLh, float* __restrict__ XR, float* __restrict__ SK, int N) {
  if (blockIdx.x < HISTBLK) {
    __shared__ int h[NB_MAX];
    for (int i = threadIdx.x; i < NB; i += blockDim.x) h[i] = 0;
    __syncthreads();
    int stride = HISTBLK * 256;
    int tid = blockIdx.x * 256 + threadIdx.x;
    if ((E & 3) == 0) {
      const int4* d4 = (const int4*)dst;
      int n4 = E >> 2;
      for (int i = tid; i < n4; i += stride) {
        int4 d = d4[i];
        atomicAdd(&h[d.x >> LBITS], 1);
        atomicAdd(&h[d.y >> LBITS], 1);
        atomicAdd(&h[d.z >> LBITS], 1);
        atomicAdd(&h[d.w >> LBITS], 1);
      }
    } else {
      for (int e = tid; e < E; e += stride) atomicAdd(&h[dst[e] >> LBITS], 1);
    }
    __syncthreads();
    for (int i = threadIdx.x; i < NB; i += blockDim.x)
      if (h[i]) atomicAdd(&bcount[i], h[i]);
  } else {
    int bx = blockIdx.x - HISTBLK;
    int mat = bx % 3;
    int node = (bx / 3) * 256 + threadIdx.x;
    if (node >= N) return;
    const float* __restrict__ W = (mat == 0) ? Wl : (mat == 1) ? Wr : Wlin;
    const float4* xr4 = (const float4*)(x + (size_t)node * F_IN);
    // Deep load pipeline: all 32 dwordx4 loads issued before the FMA chain.
    float4 xa[8], xb[8];
#pragma unroll
    for (int q = 0; q < 8; q++) xa[q] = xr4[q];
#pragma unroll
    for (int q = 0; q < 8; q++) xb[q] = xr4[8 + q];
    float acc[16];
#pragma unroll
    for (int c = 0; c < 16; c++) acc[c] = 0.f;
#pragma unroll
    for (int q = 0; q < 8; q++) {
      float xs[4] = {xa[q].x, xa[q].y, xa[q].z, xa[q].w};
#pragma unroll
      for (int j = 0; j < 4; j++) {
        int k = q * 4 + j;
#pragma unroll
        for (int c = 0; c < 16; c++) acc[c] = fmaf(xs[j], W[k * 16 + c], acc[c]);
      }
    }
#pragma unroll
    for (int q = 0; q < 8; q++) {
      float xs[4] = {xb[q].x, xb[q].y, xb[q].z, xb[q].w};
#pragma unroll
      for (int j = 0; j < 4; j++) {
        int k = 32 + q * 4 + j;
#pragma unroll
        for (int c = 0; c < 16; c++) acc[c] = fmaf(xs[j], W[k * 16 + c], acc[c]);
      }
    }
    if (mat == 0) {
      unsigned int pk[8];
#pragma unroll
      for (int i = 0; i < 8; i++)
        pk[i] = (unsigned)f2bf(acc[2 * i]) | ((unsigned)f2bf(acc[2 * i + 1]) << 16);
      uint4* xlp = (uint4*)(XLh + (size_t)node * 16);
      xlp[0] = make_uint4(pk[0], pk[1], pk[2], pk[3]);
      xlp[1] = make_uint4(pk[4], pk[5], pk[6], pk[7]);
    } else if (mat == 1) {
      float4* xrp = (float4*)(XR + (size_t)node * 16);
#pragma unroll
      for (int q = 0; q < 4; q++)
        xrp[q] = make_float4(acc[4 * q], acc[4 * q + 1], acc[4 * q + 2], acc[4 * q + 3]);
    } else {
      float4* skp = (float4*)(SK + (size_t)node * 16);
#pragma unroll
      for (int q = 0; q < 4; q++)
        skp[q] = make_float4(acc[4 * q] + blin[4 * q], acc[4 * q + 1] + blin[4 * q + 1],
                             acc[4 * q + 2] + blin[4 * q + 2], acc[4 * q + 3] + blin[4 * q + 3]);
    }
  }
}

__global__ void bucket_scan(const int* __restrict__ bcount, int* __restrict__ bbase,
                            int* __restrict__ bcursor, int NB) {
  __shared__ int sd[NB_MAX];
  int t = threadIdx.x;
  int v = (t < NB) ? bcount[t] : 0;
  sd[t] = v;
  __syncthreads();
  int acc = v;
  for (int off = 1; off < NB_MAX; off <<= 1) {
    int u = (t >= off) ? sd[t - off] : 0;
    __syncthreads();
    acc += u;
    sd[t] = acc;
    __syncthreads();
  }
  if (t < NB) {
    int excl = acc - v;
    bbase[t] = excl;
    bcursor[t] = excl;
    if (t == NB - 1) bbase[NB] = acc;
  }
}

// Phase A: block-local counting sort into LDS stage, then coalesced sweep to global.
// Bucket b's global segment is claimed via one atomicAdd per (block,bucket) pair,
// so writes are coalesced and each bucket's window stays XCD-local in phase B.
__global__ __launch_bounds__(256) void phaseA_lds(const int* __restrict__ src,
                                                  const int* __restrict__ dst,
                                                  int* __restrict__ bcursor,
                                                  int* __restrict__ packed, int E, int NB) {
  __shared__ int hist[NB_MAX];
  __shared__ int lbase[NB_MAX];
  __shared__ int gbase[NB_MAX];
  __shared__ int sdata[256];
  __shared__ int stage[EPB];
  __shared__ unsigned short stageb[EPB];
  int t = threadIdx.x;
  for (int i = t; i < NB; i += 256) hist[i] = 0;
  __syncthreads();
  int base = blockIdx.x * EPB;
  int vals[ITEMS];
  int bkt[ITEMS];
  bool vec = ((E & 3) == 0) && (base + EPB <= E);
  if (vec) {
    const int4* s4 = (const int4*)(src + base);
    const int4* d4 = (const int4*)(dst + base);
#pragma unroll
    for (int q = 0; q < ITEMS / 4; q++) {
      int idx = q * 256 + t;
      int4 sv = s4[idx];
      int4 dv = d4[idx];
      int ss[4] = {sv.x, sv.y, sv.z, sv.w};
      int dd[4] = {dv.x, dv.y, dv.z, dv.w};
#pragma unroll
      for (int r = 0; r < 4; r++) {
        int k = q * 4 + r;
        bkt[k] = dd[r] >> LBITS;
        vals[k] = (ss[r] << LBITS) | (dd[r] & (LOCAL - 1));
        atomicAdd(&hist[bkt[k]], 1);
      }
    }
  } else {
#pragma unroll
    for (int k = 0; k < ITEMS; k++) {
      int e = base + k * 256 + t;
      if (e < E) {
        int s = src[e];
        int d = dst[e];
        bkt[k] = d >> LBITS;
        vals[k] = (s << LBITS) | (d & (LOCAL - 1));
        atomicAdd(&hist[bkt[k]], 1);
      } else {
        bkt[k] = -1;
      }
    }
  }
  __syncthreads();
  int i0 = 2 * t, i1 = 2 * t + 1;
  int h0 = (i0 < NB) ? hist[i0] : 0;
  int h1 = (i1 < NB) ? hist[i1] : 0;
  int s2 = h0 + h1;
  sdata[t] = s2;
  __syncthreads();
  int acc = s2;
  for (int off = 1; off < 256; off <<= 1) {
    int u = (t >= off) ? sdata[t - off] : 0;
    __syncthreads();
    acc += u;
    sdata[t] = acc;
    __syncthreads();
  }
  int excl = acc - s2;
  if (i0 < NB) lbase[i0] = excl;
  if (i1 < NB) lbase[i1] = excl + h0;
  __syncthreads();
  for (int i = t; i < NB; i += 256) {
    int c = hist[i];
    gbase[i] = c ? atomicAdd(&bcursor[i], c) : 0;
    hist[i] = lbase[i];
  }
  __syncthreads();
  if (vec) {
#pragma unroll
    for (int k = 0; k < ITEMS; k++) {
      int lp = atomicAdd(&hist[bkt[k]], 1);
      stage[lp] = vals[k];
      stageb[lp] = (unsigned short)bkt[k];
    }
  } else {
#pragma unroll
    for (int k = 0; k < ITEMS; k++) {
      if (bkt[k] >= 0) {
        int lp = atomicAdd(&hist[bkt[k]], 1);
        stage[lp] = vals[k];
        stageb[lp] = (unsigned short)bkt[k];
      }
    }
  }
  __syncthreads();
  int blockE = E - base;
  if (blockE > EPB) blockE = EPB;
  for (int i = t; i < blockE; i += 256) {
    int b = stageb[i];
    packed[gbase[b] + (i - lbase[b])] = stage[i];
  }
}

// Phase B: per-bucket counting sort; ssrc packs (src<<5)|(node&31).
// 512 threads (was 256): grid is only NB=391 blocks (~1.5/CU), so doubling
// waves/block halves the edge-pass trip count and improves latency hiding.
// Scan is padded to a uniform 512-wide scan (zeros above 256) so all
// __syncthreads are non-divergent.
__global__ __launch_bounds__(512) void phaseB_sort(const int* __restrict__ packed,
                                                   const int* __restrict__ bbase,
                                                   int* __restrict__ row_ptr,
                                                   int* __restrict__ ssrc, int N, int E) {
  __shared__ int h[LOCAL];
  __shared__ int sd[512];
  int b = blockIdx.x;
  int t = threadIdx.x;
  int beg = bbase[b], end = bbase[b + 1];
  int node0 = b << LBITS;
  if (t < LOCAL) h[t] = 0;
  __syncthreads();
  for (int j = beg + t; j < end; j += 512) atomicAdd(&h[packed[j] & (LOCAL - 1)], 1);
  __syncthreads();
  int cnt = (t < LOCAL) ? h[t] : 0;
  sd[t] = cnt;
  __syncthreads();
  int acc = cnt;
  for (int off = 1; off < 512; off <<= 1) {
    int u = (t >= off) ? sd[t - off] : 0;
    __syncthreads();
    acc += u;
    sd[t] = acc;
    __syncthreads();
  }
  if (t < LOCAL) {
    int myex = acc - cnt;
    int node = node0 + t;
    if (node < N) row_ptr[node] = beg + myex;
    h[t] = beg + myex;
  }
  if (b == gridDim.x - 1 && t == 0) row_ptr[N] = E;
  __syncthreads();
  for (int j = beg + t; j < end; j += 512) {
    int v = packed[j];
    int l = v & (LOCAL - 1);
    int p = atomicAdd(&h[l], 1);
    ssrc[p] = ((v >> LBITS) << 5) | (l & 31);
  }
}

// ---------------- GAT layer ----------------
// hsh aliases vpool (dead after phase 2; barrier-protected) to save LDS -> 7 blocks/CU.
template <int C, int POOL, bool HEAD, bool FUSEG2>
__global__ __launch_bounds__(256) void gat_layer(
    const __hip_bfloat16* __restrict__ XLh, const float* __restrict__ XR,
    const float* __restrict__ SK, const float* __restrict__ att, const float* __restrict__ bias,
    const float* __restrict__ tp, const int* __restrict__ row_ptr, const int* __restrict__ ssrc,
    float* __restrict__ H, int N,
    const float* __restrict__ P0, const float* __restrict__ P1, const float* __restrict__ P2,
    const float* __restrict__ P3, const float* __restrict__ P4, const float* __restrict__ P5,
    const float* __restrict__ P6, const float* __restrict__ P7,
    __hip_bfloat16* __restrict__ XL2h, float* __restrict__ XR2, float* __restrict__ SK2,
    float* __restrict__ out) {
  constexpr int NPB = 256 / C;
  __shared__ __align__(16) unsigned short vpool[POOL * C];
  __shared__ float ppool[POOL];
  __shared__ __align__(16) float xrl[NPB * C];
  __shared__ int nb[NPB + 1];
  __shared__ float wfuse[FUSEG2 ? 392 : 1];
  float* hsh = (float*)vpool;  // aliased: used only after phase 2 (barrier-protected)
  int t = threadIdx.x;
  int node0 = blockIdx.x * NPB;

  if (t <= NPB) {
    int nd = node0 + t;
    nb[t] = row_ptr[(nd < N) ? nd : N];
  }
  {
    size_t xi = (size_t)node0 * C + t;
    xrl[t] = (xi < (size_t)N * C) ? XR[xi] : 0.f;
  }
  if constexpr (FUSEG2) {
    for (int i = t; i < 392; i += 256)
      wfuse[i] = (i < 128) ? P0[i] : (i < 256) ? P1[i - 128] : (i < 384) ? P2[i - 256] : P3[i - 384];
  }
  float attr[C];
#pragma unroll
  for (int cc = 0; cc < C; cc++) attr[cc] = att[cc];
  float tval = tp[0];
  __syncthreads();

  int bbeg = nb[0];
  int nE = nb[NPB] - bbeg;
  int nCap = (nE < POOL) ? nE : POOL;
  const unsigned short* XLu = (const unsigned short*)XLh;

  // ---- Phase S: edge-per-lane gather + score ----
  for (int slot = t; slot < nCap; slot += 256) {
    int sp = ssrc[bbeg + slot];
    int s = sp >> 5;
    int g = sp & (NPB - 1);
    float v[C];
    if constexpr (C == 16) {
      const uint4* gp = (const uint4*)(XLu + (size_t)s * 16);
      uint4 a = gp[0], b = gp[1];
      *(uint4*)&vpool[slot * 16] = a;
      *(uint4*)&vpool[slot * 16 + 8] = b;
      unsigned arr[8] = {a.x, a.y, a.z, a.w, b.x, b.y, b.z, b.w};
#pragma unroll
      for (int i = 0; i < 8; i++) {
        v[2 * i] = __uint_as_float(arr[i] << 16);
        v[2 * i + 1] = __uint_as_float(arr[i] & 0xffff0000u);
      }
    } else {
      const uint4* gp = (const uint4*)(XLu + (size_t)s * 8);
      uint4 a = gp[0];
      *(uint4*)&vpool[slot * 8] = a;
      unsigned arr[4] = {a.x, a.y, a.z, a.w};
#pragma unroll
      for (int i = 0; i < 4; i++) {
        v[2 * i] = __uint_as_float(arr[i] << 16);
        v[2 * i + 1] = __uint_as_float(arr[i] & 0xffff0000u);
      }
    }
    float xr[C];
    const float4* xp = (const float4*)&xrl[g * C];
#pragma unroll
    for (int q = 0; q < C / 4; q++) {
      float4 f = xp[q];
      xr[4 * q] = f.x;
      xr[4 * q + 1] = f.y;
      xr[4 * q + 2] = f.z;
      xr[4 * q + 3] = f.w;
    }
    float p0 = 0.f, p1 = 0.f, p2 = 0.f, p3 = 0.f;
#pragma unroll
    for (int cc = 0; cc < C; cc += 4) {
      float u0 = v[cc] + xr[cc];
      float u1 = v[cc + 1] + xr[cc + 1];
      float u2 = v[cc + 2] + xr[cc + 2];
      float u3 = v[cc + 3] + xr[cc + 3];
      p0 = fmaf(fmaxf(u0, 0.2f * u0), attr[cc], p0);
      p1 = fmaf(fmaxf(u1, 0.2f * u1), attr[cc + 1], p1);
      p2 = fmaf(fmaxf(u2, 0.2f * u2), attr[cc + 2], p2);
      p3 = fmaf(fmaxf(u3, 0.2f * u3), attr[cc + 3], p3);
    }
    ppool[slot] = __expf((p0 + p1) + (p2 + p3));
  }
  __syncthreads();

  int g = t / C;
  int c = t % C;
  int base = nb[g] - bbeg;
  int deg = nb[g + 1] - nb[g];
  int capd = POOL - base;
  capd = capd < 0 ? 0 : (capd > deg ? deg : capd);

  // ---- Phase D: S0 per node ----
  float invS0;
  {
    float s0 = 0.f;
    for (int j = c; j < capd; j += C) s0 += ppool[base + j];
    for (int j = capd + c; j < deg; j += C) {  // overflow fallback (rare)
      int s = ssrc[bbeg + base + j] >> 5;
      float sc = 0.f;
#pragma unroll
      for (int cc = 0; cc < C; cc++) {
        float v = __bfloat162float(XLh[(size_t)s * C + cc]);
        float u = v + xrl[g * C + cc];
        sc = fmaf(fmaxf(u, 0.2f * u), attr[cc], sc);
      }
      s0 += __expf(sc);
    }
#pragma unroll
    for (int m = 1; m < C; m <<= 1) s0 += __shfl_xor(s0, m, C);
    invS0 = (deg > 0) ? 1.0f / s0 : 0.f;
  }
  float a = invS0 * tval;

  // ---- Phase 2: q = v*p*a; w = exp(q); S1 += w; S2 += w*q ----
  float S1 = 0.f, S2 = 0.f, S1b = 0.f, S2b = 0.f;
  int jj = 0;
  for (; jj + 2 <= capd; jj += 2) {
    int sl0 = base + jj;
    float v0 = __uint_as_float(((unsigned)vpool[sl0 * C + c]) << 16);
    float q0 = v0 * ppool[sl0] * a;
    float v1 = __uint_as_float(((unsigned)vpool[(sl0 + 1) * C + c]) << 16);
    float q1 = v1 * ppool[sl0 + 1] * a;
    float w0 = __expf(q0);
    float w1 = __expf(q1);
    S1 += w0;
    S2 = fmaf(w0, q0, S2);
    S1b += w1;
    S2b = fmaf(w1, q1, S2b);
  }
  for (; jj < capd; jj++) {
    int sl = base + jj;
    float v = __uint_as_float(((unsigned)vpool[sl * C + c]) << 16);
    float q = v * ppool[sl] * a;
    float w = __expf(q);
    S1 += w;
    S2 = fmaf(w, q, S2);
  }
  for (; jj < deg; jj++) {  // overflow fallback (rare)
    int s = ssrc[bbeg + base + jj] >> 5;
    float sc = 0.f, vc = 0.f;
#pragma unroll
    for (int cc = 0; cc < C; cc++) {
      float v = __bfloat162float(XLh[(size_t)s * C + cc]);
      if (cc == c) vc = v;
      float u = v + xrl[g * C + cc];
      sc = fmaf(fmaxf(u, 0.2f * u), attr[cc], sc);
    }
    float p = __expf(sc);
    float q = vc * p * a;
    float w = __expf(q);
    S1 += w;
    S2 = fmaf(w, q, S2);
  }
  S1 += S1b;
  S2 += S2b;

  int node = node0 + g;
  bool valid = node < N;
  float hval = 0.f;
  if (valid) {
    float td = (tval != 0.f) ? tval : 1.f;
    float gat = (deg > 0) ? (S2 / (S1 * td)) : 0.f;
    hval = fmaxf(gat + bias[c] + SK[(size_t)node * C + c], 0.f);
  }
  if constexpr (FUSEG2) {
    __syncthreads();  // vpool dead; hsh aliases it
    hsh[g * C + c] = hval;
    __syncthreads();
    if (t < NPB * 8) {
      int g2 = t >> 3, c2 = t & 7;
      int nd = node0 + g2;
      if (nd < N) {
        float a0 = 0.f, a1 = 0.f, a2 = 0.f;
#pragma unroll
        for (int k = 0; k < 16; k++) {
          float hv = hsh[g2 * 16 + k];
          a0 = fmaf(hv, wfuse[k * 8 + c2], a0);
          a1 = fmaf(hv, wfuse[128 + k * 8 + c2], a1);
          a2 = fmaf(hv, wfuse[256 + k * 8 + c2], a2);
        }
        ((unsigned short*)XL2h)[(size_t)nd * 8 + c2] = f2bf(a0);
        XR2[(size_t)nd * 8 + c2] = a1;
        SK2[(size_t)nd * 8 + c2] = a2 + wfuse[384 + c2];
      }
    }
  } else if constexpr (HEAD) {
    __syncthreads();  // vpool dead; hsh aliases it
    hsh[g * C + c] = hval;
    __syncthreads();
    if (t < NPB) {
      int nd = node0 + t;
      if (nd < N) {
        float h[8];
#pragma unroll
        for (int k = 0; k < 8; k++) h[k] = hsh[t * 8 + k];
        float s4 = 0.f;
#pragma unroll
        for (int cc = 0; cc < 8; cc++) {
          float z = P1[cc];  // b3
#pragma unroll
          for (int k = 0; k < 8; k++) z = fmaf(h[k], P0[k * 8 + cc], z);  // W3
          z = fmaxf(z, 0.f);
          s4 = fmaf(z, P2[cc], s4);  // W4
        }
        s4 = fmaxf(s4 + P3[0], 0.f);                    // b4
        float s5 = fmaxf(fmaf(s4, P4[0], P5[0]), 0.f);  // W5,b5
        float zo = fmaf(s5, P6[0], P7[0]);              // Wout,bout
        float ls;
        if (zo >= 0.f)
          ls = -log1pf(expf(-zo));
        else
          ls = zo - log1pf(expf(zo));
        out[nd] = ls;
      }
    }
  } else {
    if (valid) H[(size_t)node * C + c] = hval;
  }
}

extern "C" void kernel_launch(void* const* d_in, const int* in_sizes, int n_in,
                              void* d_out, int out_size, void* d_ws, size_t ws_size,
                              hipStream_t stream) {
  const float* x = (const float*)d_in[0];
  const int* ei = (const int*)d_in[1];
  const float* Wl1 = (const float*)d_in[3];
  const float* Wr1 = (const float*)d_in[4];
  const float* att1 = (const float*)d_in[5];
  const float* b1 = (const float*)d_in[6];
  const float* Wlin1 = (const float*)d_in[7];
  const float* blin1 = (const float*)d_in[8];
  const float* Wl2 = (const float*)d_in[9];
  const float* Wr2 = (const float*)d_in[10];
  const float* att2 = (const float*)d_in[11];
  const float* b2 = (const float*)d_in[12];
  const float* Wlin2 = (const float*)d_in[13];
  const float* blin2 = (const float*)d_in[14];
  const float* t = (const float*)d_in[15];
  const float* W3 = (const float*)d_in[16];
  const float* b3 = (const float*)d_in[17];
  const float* W4 = (const float*)d_in[18];
  const float* b4 = (const float*)d_in[19];
  const float* W5 = (const float*)d_in[20];
  const float* b5 = (const float*)d_in[21];
  const float* Wout = (const float*)d_in[22];
  const float* bout = (const float*)d_in[23];
  float* out = (float*)d_out;

  int N = in_sizes[0] / F_IN;
  int E = in_sizes[1] / 2;
  const int* src = ei;
  const int* dst = ei + E;
  int NB = (N + LOCAL - 1) >> LBITS;  // 391 for N=100000

  char* ws = (char*)d_ws;
  size_t off = 0;
  auto alloc = [&](size_t bytes) -> void* {
    void* p = ws + off;
    off = (off + bytes + 255) & ~(size_t)255;
    return p;
  };
  int* bcount = (int*)alloc((size_t)NB * 4);
  int* bbase = (int*)alloc((size_t)(NB + 1) * 4);
  int* bcursor = (int*)alloc((size_t)NB * 4);
  int* packed = (int*)alloc((size_t)E * 4);
  int* row_ptr = (int*)alloc((size_t)(N + 1) * 4);
  int* ssrc = (int*)alloc((size_t)E * 4);
  __hip_bfloat16* XL1 = (__hip_bfloat16*)alloc((size_t)N * C1 * 2);
  float* XR1 = (float*)alloc((size_t)N * C1 * 4);
  float* SK1 = (float*)alloc((size_t)N * C1 * 4);
  __hip_bfloat16* XL2 = (__hip_bfloat16*)alloc((size_t)N * C2 * 2);
  float* XR2 = (float*)alloc((size_t)N * C2 * 4);
  float* SK2 = (float*)alloc((size_t)N * C2 * 4);

  int nblkA = (E + EPB - 1) / EPB;
  int nodeBlk = (N + 255) / 256;  // 391

  hipMemsetAsync(bcount, 0, (size_t)NB * 4, stream);
  hipLaunchKernelGGL(hist_gemm, dim3(HISTBLK + nodeBlk * 3), dim3(256), 0, stream, dst, bcount, E,
                     NB, x, Wl1, Wr1, Wlin1, blin1, XL1, XR1, SK1, N);
  hipLaunchKernelGGL(bucket_scan, dim3(1), dim3(NB_MAX), 0, stream, bcount, bbase, bcursor, NB);
  hipLaunchKernelGGL(phaseA_lds, dim3(nblkA), dim3(256), 0, stream, src, dst, bcursor, packed, E,
                     NB);
  hipLaunchKernelGGL(phaseB_sort, dim3(NB), dim3(512), 0, stream, packed, bbase, row_ptr, ssrc, N,
                     E);
  hipLaunchKernelGGL((gat_layer<16, 576, false, true>), dim3((N + 15) / 16), dim3(256), 0, stream,
                     XL1, XR1, SK1, att1, b1, t, row_ptr, ssrc, nullptr, N, Wl2, Wr2, Wlin2, blin2,
                     nullptr, nullptr, nullptr, nullptr, XL2, XR2, SK2, nullptr);
  hipLaunchKernelGGL((gat_layer<8, 1216, true, false>), dim3((N + 31) / 32), dim3(256), 0, stream,
                     XL2, XR2, SK2, att2, b2, t, row_ptr, ssrc, nullptr, N, W3, b3, W4, b4, W5, b5,
                     Wout, bout, nullptr, nullptr, nullptr, out);
}